// Round 3
// baseline (167.456 us; speedup 1.0000x reference)
//
#include <hip/hip_runtime.h>

#define MAXLEN 20
#define DIM 1024
#define NB 16384
#define RPB 4                 // rows per block
#define NBLK (NB / RPB)       // 4096 blocks -> 16/CU assigned, ~8 resident: dynamic backfill

// Block handles RPB consecutive rows; 256 threads, thread i owns float4 slot i
// of the 1024-wide feature dim. alpha=0.5 -> all weights are exact powers of 2:
// w[t] = 2^-(L-1-t) / (2*(1-2^-L)). Next row's mask (80 B, lane-uniform ->
// scalar loads) is issued BEFORE the current row's token loop so the
// mask->L->loads dependency chain never stalls the pipe after row 0.
__global__ __launch_bounds__(256) void tdap_kernel(
    const float* __restrict__ x,     // [NB, MAXLEN, DIM]
    const int*   __restrict__ mask,  // [NB, MAXLEN]
    float*       __restrict__ out)   // [NB, DIM]
{
    const int tid  = threadIdx.x;           // 0..255
    const int row0 = blockIdx.x * RPB;

    // Prefetch mask for the first row (5 x int4 = 80 B, 16B-aligned: 80*row0).
    const int4* mrow = reinterpret_cast<const int4*>(mask + (size_t)row0 * MAXLEN);
    int4 m0 = mrow[0], m1 = mrow[1], m2 = mrow[2], m3 = mrow[3], m4 = mrow[4];

    for (int k = 0; k < RPB; ++k) {
        const int r = row0 + k;

        const int L = m0.x + m0.y + m0.z + m0.w
                    + m1.x + m1.y + m1.z + m1.w
                    + m2.x + m2.y + m2.z + m2.w
                    + m3.x + m3.y + m3.z + m3.w
                    + m4.x + m4.y + m4.z + m4.w;

        // Issue next row's mask loads now; consume after the token loop.
        int4 n0, n1, n2, n3, n4;
        if (k + 1 < RPB) {
            const int4* nrow = reinterpret_cast<const int4*>(mask + (size_t)(r + 1) * MAXLEN);
            n0 = nrow[0]; n1 = nrow[1]; n2 = nrow[2]; n3 = nrow[3]; n4 = nrow[4];
        }

        // norm = sum_{j=0}^{L-1} 0.5^j = 2*(1-2^-L), exact in fp32 for L<=20.
        const float inv_norm = 1.0f / (2.0f * (1.0f - ldexpf(1.0f, -L)));
        float w = ldexpf(1.0f, -(L - 1)) * inv_norm;  // weight of token 0

        const float4* xp = reinterpret_cast<const float4*>(x + (size_t)r * MAXLEN * DIM) + tid;

        float4 a0 = make_float4(0.f, 0.f, 0.f, 0.f);
        float4 a1 = make_float4(0.f, 0.f, 0.f, 0.f);
        float4 a2 = make_float4(0.f, 0.f, 0.f, 0.f);
        float4 a3 = make_float4(0.f, 0.f, 0.f, 0.f);

        int t = 0;
        for (; t + 4 <= L; t += 4) {   // 4 tokens/iter, 4 KB/wave in flight
            float4 v0 = xp[(size_t)(t + 0) * (DIM / 4)];
            float4 v1 = xp[(size_t)(t + 1) * (DIM / 4)];
            float4 v2 = xp[(size_t)(t + 2) * (DIM / 4)];
            float4 v3 = xp[(size_t)(t + 3) * (DIM / 4)];
            a0.x = fmaf(w, v0.x, a0.x); a0.y = fmaf(w, v0.y, a0.y);
            a0.z = fmaf(w, v0.z, a0.z); a0.w = fmaf(w, v0.w, a0.w);
            a1.x = fmaf(w, v1.x, a1.x); a1.y = fmaf(w, v1.y, a1.y);
            a1.z = fmaf(w, v1.z, a1.z); a1.w = fmaf(w, v1.w, a1.w);
            a2.x = fmaf(w, v2.x, a2.x); a2.y = fmaf(w, v2.y, a2.y);
            a2.z = fmaf(w, v2.z, a2.z); a2.w = fmaf(w, v2.w, a2.w);
            a3.x = fmaf(w, v3.x, a3.x); a3.y = fmaf(w, v3.y, a3.y);
            a3.z = fmaf(w, v3.z, a3.z); a3.w = fmaf(w, v3.w, a3.w);
            w *= 16.0f;  // exact power-of-two scale
        }
        for (; t < L; ++t) {           // tail 0..3 tokens
            float4 v = xp[(size_t)t * (DIM / 4)];
            a0.x = fmaf(w, v.x, a0.x); a0.y = fmaf(w, v.y, a0.y);
            a0.z = fmaf(w, v.z, a0.z); a0.w = fmaf(w, v.w, a0.w);
            w *= 2.0f;
        }

        // acc = a0 + 2*a1 + 4*a2 + 8*a3 (exact scales).
        float4 acc;
        acc.x = fmaf(8.f, a3.x, fmaf(4.f, a2.x, fmaf(2.f, a1.x, a0.x)));
        acc.y = fmaf(8.f, a3.y, fmaf(4.f, a2.y, fmaf(2.f, a1.y, a0.y)));
        acc.z = fmaf(8.f, a3.z, fmaf(4.f, a2.z, fmaf(2.f, a1.z, a0.z)));
        acc.w = fmaf(8.f, a3.w, fmaf(4.f, a2.w, fmaf(2.f, a1.w, a0.w)));

        reinterpret_cast<float4*>(out + (size_t)r * DIM)[tid] = acc;

        if (k + 1 < RPB) { m0 = n0; m1 = n1; m2 = n2; m3 = n3; m4 = n4; }
    }
}

extern "C" void kernel_launch(void* const* d_in, const int* in_sizes, int n_in,
                              void* d_out, int out_size, void* d_ws, size_t ws_size,
                              hipStream_t stream) {
    const float* x    = (const float*)d_in[0];
    const int*   mask = (const int*)d_in[1];
    float*       out  = (float*)d_out;
    tdap_kernel<<<NBLK, 256, 0, stream>>>(x, mask, out);
}

// Round 5
// 141.518 us; speedup vs baseline: 1.1833x; 1.1833x over previous
//
#include <hip/hip_runtime.h>

#define MAXLEN 20
#define DIM 1024
#define NB 16384

// clang-native vector types (HIP_vector_type float4 is rejected by
// __builtin_nontemporal_load/store).
typedef float vf4 __attribute__((ext_vector_type(4)));
typedef int   vi4 __attribute__((ext_vector_type(4)));

// One block per row. 256 threads; thread i owns 16B slot i of D=1024.
// alpha=0.5 -> weights are exact powers of two: w[t] = 2^-(L-1-t) / (2*(1-2^-L)).
// Token 0 is always valid (L >= 1), so its load is issued BEFORE the mask sum
// is consumed -- the mask->L->x dependency chain and the first x-load latency
// overlap instead of serializing. Nontemporal on the zero-reuse x/out streams.
__global__ __launch_bounds__(256, 8) void tdap_kernel(
    const float* __restrict__ x,     // [NB, MAXLEN, DIM]
    const int*   __restrict__ mask,  // [NB, MAXLEN]
    float*       __restrict__ out)   // [NB, DIM]
{
    const int b   = blockIdx.x;
    const int tid = threadIdx.x;  // 0..255

    const vf4* xp = reinterpret_cast<const vf4*>(x + (size_t)b * MAXLEN * DIM) + tid;

    // Speculative token-0 load (always in-bounds), concurrent with mask loads.
    vf4 v0 = __builtin_nontemporal_load(&xp[0]);

    // Mask row: 80 B, lane-uniform address -> scalar loads.
    const vi4* mrow = reinterpret_cast<const vi4*>(mask + (size_t)b * MAXLEN);
    vi4 m0 = mrow[0], m1 = mrow[1], m2 = mrow[2], m3 = mrow[3], m4 = mrow[4];
    const int L = m0.x + m0.y + m0.z + m0.w
                + m1.x + m1.y + m1.z + m1.w
                + m2.x + m2.y + m2.z + m2.w
                + m3.x + m3.y + m3.z + m3.w
                + m4.x + m4.y + m4.z + m4.w;

    // norm = sum_{k=0}^{L-1} 0.5^k = 2*(1-2^-L), exact in fp32 for L<=20.
    const float inv_norm = 1.0f / (2.0f * (1.0f - ldexpf(1.0f, -L)));
    float w = ldexpf(1.0f, -(L - 1)) * inv_norm;  // weight of token 0

    vf4 a0 = w * v0;
    vf4 a1 = (vf4)0.0f;
    vf4 a2 = (vf4)0.0f;
    vf4 a3 = (vf4)0.0f;

    int t = 1;
    w *= 2.0f;  // weight of token 1
    // Main: 4 tokens/iter; token t+j carries weight w*2^j, folded in epilogue.
    for (; t + 4 <= L; t += 4) {
        vf4 u0 = __builtin_nontemporal_load(&xp[(size_t)(t + 0) * (DIM / 4)]);
        vf4 u1 = __builtin_nontemporal_load(&xp[(size_t)(t + 1) * (DIM / 4)]);
        vf4 u2 = __builtin_nontemporal_load(&xp[(size_t)(t + 2) * (DIM / 4)]);
        vf4 u3 = __builtin_nontemporal_load(&xp[(size_t)(t + 3) * (DIM / 4)]);
        a0 += w * u0;
        a1 += w * u1;
        a2 += w * u2;
        a3 += w * u3;
        w *= 16.0f;  // exact power-of-two scale
    }
    for (; t < L; ++t) {  // tail 0..3 tokens, multiplier 1 -> a0
        vf4 u = __builtin_nontemporal_load(&xp[(size_t)t * (DIM / 4)]);
        a0 += w * u;
        w *= 2.0f;
    }

    // acc = a0 + 2*a1 + 4*a2 + 8*a3 (exact power-of-two scales).
    vf4 acc = a0 + 2.0f * a1 + 4.0f * a2 + 8.0f * a3;

    __builtin_nontemporal_store(acc, reinterpret_cast<vf4*>(out + (size_t)b * DIM) + tid);
}

extern "C" void kernel_launch(void* const* d_in, const int* in_sizes, int n_in,
                              void* d_out, int out_size, void* d_ws, size_t ws_size,
                              hipStream_t stream) {
    const float* x    = (const float*)d_in[0];
    const int*   mask = (const int*)d_in[1];
    float*       out  = (float*)d_out;
    tdap_kernel<<<NB, 256, 0, stream>>>(x, mask, out);
}